// Round 3
// baseline (113.281 us; speedup 1.0000x reference)
//
#include <hip/hip_runtime.h>
#include <hip/hip_bf16.h>
#include <stdint.h>

#define NROWS 8192
#define NDIM  512
#define MARGIN 0.3f
#define NRB   32               // 256-row blocks
#define NT    528              // 32*33/2 upper-triangular 256x256 tiles

typedef __attribute__((ext_vector_type(16))) float floatx16;
typedef __attribute__((ext_vector_type(8)))  int   intx8;

// pack 4 floats -> 4 OCP e4m3 bytes (HW cvt, RNE, saturating)
__device__ inline unsigned cvt4_fp8(float4 f) {
  int v = 0;
  v = __builtin_amdgcn_cvt_pk_fp8_f32(f.x, f.y, v, false);
  v = __builtin_amdgcn_cvt_pk_fp8_f32(f.z, f.w, v, true);
  return (unsigned)v;
}

// fp32 -> fp8 e4m3, fully coalesced: lane i reads float4 i, writes u32 i
__global__ void convert_kernel(const float4* __restrict__ in, unsigned* __restrict__ out) {
  int i = blockIdx.x * blockDim.x + threadIdx.x;
  out[i] = cvt4_fp8(in[i]);
}

__device__ inline void gload_lds16(const void* g, void* l) {
  __builtin_amdgcn_global_load_lds(
      (const __attribute__((address_space(1))) unsigned int*)g,
      (__attribute__((address_space(3))) unsigned int*)l, 16, 0, 0);
}

// R18: 256x256 tiles (2x arithmetic intensity vs 128x128 -> staged traffic
// 266 MB -> 135 MB; loss was staging-BW-bound at ~6.2 TB/s under the harness
// poison-writeback storm that thrashes L3). 8 waves (4x2 of 64x128), acc[2][4],
// LDS 3-stage x (256+256 rows x 64 B) = 96 KB, 1 block/CU. Pipeline = the
// R15-proven skeleton: per-wave 4 DMA loads/stage, distance-2 prefetch,
// per-wave s_waitcnt vmcnt(4) mid-loop (own stage landed, next in flight),
// raw s_barrier (no lgkm drain), stage-after-barrier (WAR barrier-ordered).
// Label epilogue (R0-proven, absmax 0.0): pos/neg via targets, x2 off-diag,
// diag weighted row<col.
__launch_bounds__(512, 1)
__global__ void loss_kernel(const unsigned char* __restrict__ Xb, const int* __restrict__ tg,
                            float* __restrict__ partials) {
  __shared__ __align__(16) unsigned char As[3][16384];  // 256 rows x 64 B
  __shared__ __align__(16) unsigned char Bs[3][16384];
  __shared__ float red[8];

  // row-major upper-tri decode: consecutive blocks share bi (A-band locality)
  int t = blockIdx.x, bi = 0;
  while (t >= NRB - bi) { t -= NRB - bi; bi++; }
  const int bj = bi + t;

  const int tid  = threadIdx.x;
  const int lane = tid & 63;
  const int w    = tid >> 6;             // 0..7
  const int wm   = w >> 1, wn = w & 1;   // 4x2 waves, 64x128 each
  const int g    = lane >> 5;            // MFMA k-group (0/1)
  const int m32  = lane & 31;            // MFMA row/col within 32

  const int rowBase = bi * 256;
  const int colBase = bj * 256;

  // staging: tile = 256 rows x 64 B = 16 chunks of 1 KB (16 rows each);
  // wave w stages chunks {2w, 2w+1} of A and of B (4 DMA loads/wave/stage).
  // Chunk lane d: row = ch*16 + (d>>2), u_phys = d&3; fetches global k-unit
  // u_log = u_phys ^ ((row>>2)&3)  (conflict-free b128 reads, R14-verified).
  const int srow = lane >> 2;
  const int sup  = lane & 3;
  unsigned gA[2], gB[2];
#pragma unroll
  for (int c = 0; c < 2; c++) {
    int ch  = w * 2 + c;                 // 0..15
    int row = ch * 16 + srow;            // 0..255
    int ul  = sup ^ ((row >> 2) & 3);
    gA[c] = (unsigned)((rowBase + row) * NDIM + ul * 16);
    gB[c] = (unsigned)((colBase + row) * NDIM + ul * 16);
  }

#define STAGE(KT, BUF)                                                    \
  do {                                                                    \
    _Pragma("unroll")                                                     \
    for (int c = 0; c < 2; c++) {                                         \
      int ch = w * 2 + c;                                                 \
      gload_lds16(Xb + gA[c] + (KT) * 64, &As[BUF][ch * 1024]);           \
      gload_lds16(Xb + gB[c] + (KT) * 64, &Bs[BUF][ch * 1024]);           \
    }                                                                     \
  } while (0)

  floatx16 acc[2][4];
#pragma unroll
  for (int a = 0; a < 2; a++)
#pragma unroll
    for (int b = 0; b < 4; b++) acc[a][b] = (floatx16)(0.f);

  STAGE(0, 0);
  STAGE(1, 1);

#pragma unroll
  for (int kt = 0; kt < 8; kt++) {
    const int buf = kt % 3;
    // own stage kt landed (4 oldest loads retired); kt+1's 4 stay in flight.
    if (kt < 7) asm volatile("s_waitcnt vmcnt(4)" ::: "memory");
    else        asm volatile("s_waitcnt vmcnt(0)" ::: "memory");
    asm volatile("s_barrier" ::: "memory");        // raw: no lgkm drain
    if (kt < 6) STAGE(kt + 2, (kt + 2) % 3);       // distance-2 prefetch

    // fragments: lane holds k = g*32 + [0,32) of its row as 2 x b128
    // (u_log = 2g, 2g+1), un-swizzled via u_phys = u_log ^ ((row>>2)&3)
    intx8 af[2], bf[4];
#pragma unroll
    for (int mt = 0; mt < 2; mt++) {
      const int row = wm * 64 + mt * 32 + m32;
      const int x = (row >> 2) & 3;
      int4 lo = *(const int4*)(&As[buf][row * 64 + ((2 * g)     ^ x) * 16]);
      int4 hi = *(const int4*)(&As[buf][row * 64 + ((2 * g + 1) ^ x) * 16]);
      intx8 f; f[0]=lo.x; f[1]=lo.y; f[2]=lo.z; f[3]=lo.w;
               f[4]=hi.x; f[5]=hi.y; f[6]=hi.z; f[7]=hi.w;
      af[mt] = f;
    }
#pragma unroll
    for (int nt = 0; nt < 4; nt++) {
      const int row = wn * 128 + nt * 32 + m32;
      const int x = (row >> 2) & 3;
      int4 lo = *(const int4*)(&Bs[buf][row * 64 + ((2 * g)     ^ x) * 16]);
      int4 hi = *(const int4*)(&Bs[buf][row * 64 + ((2 * g + 1) ^ x) * 16]);
      intx8 f; f[0]=lo.x; f[1]=lo.y; f[2]=lo.z; f[3]=lo.w;
               f[4]=hi.x; f[5]=hi.y; f[6]=hi.z; f[7]=hi.w;
      bf[nt] = f;
    }
#pragma unroll
    for (int mt = 0; mt < 2; mt++)
#pragma unroll
      for (int nt = 0; nt < 4; nt++)
        acc[mt][nt] = __builtin_amdgcn_mfma_scale_f32_32x32x64_f8f6f4(
            af[mt], bf[nt], acc[mt][nt],
            0 /*A fmt: fp8 e4m3*/, 0 /*B fmt: fp8 e4m3*/,
            0, 127 /*scaleA = 2^0*/, 0, 127 /*scaleB = 2^0*/);
  }

  // Epilogue (R0-verified logic). 32x32 C/D layout [m74/m101]: col = lane&31,
  // row = (reg&3) + 8*(reg>>2) + 4*(lane>>5), reg in [0,16).
  float lsum = 0.f;
  const bool diag = (bi == bj);
  if (!diag) {
#pragma unroll
    for (int mt = 0; mt < 2; mt++) {
#pragma unroll
      for (int nt = 0; nt < 4; nt++) {
        const int tc = tg[colBase + wn * 128 + nt * 32 + m32];
#pragma unroll
        for (int q = 0; q < 4; q++) {
          const int4 rlv = *(const int4*)(tg + rowBase + wm * 64 + mt * 32 + 4 * g + 8 * q);
          const int rlab[4] = {rlv.x, rlv.y, rlv.z, rlv.w};
#pragma unroll
          for (int j = 0; j < 4; j++) {
            const float s = acc[mt][nt][q * 4 + j];
            lsum += (rlab[j] == tc) ? ((s < 1.f) ? 1.f - s : 0.f)
                                    : ((s > MARGIN) ? s : 0.f);
          }
        }
      }
    }
    lsum *= 2.f;     // pair weight hoisted
  } else {
#pragma unroll
    for (int mt = 0; mt < 2; mt++) {
#pragma unroll
      for (int nt = 0; nt < 4; nt++) {
        const int cloc = wn * 128 + nt * 32 + m32;
        const int tc = tg[colBase + cloc];
        const int col = colBase + cloc;
#pragma unroll
        for (int q = 0; q < 4; q++) {
          const int rbase = wm * 64 + mt * 32 + 4 * g + 8 * q;
          const int4 rlv = *(const int4*)(tg + rowBase + rbase);
          const int rlab[4] = {rlv.x, rlv.y, rlv.z, rlv.w};
#pragma unroll
          for (int j = 0; j < 4; j++) {
            const float s = acc[mt][nt][q * 4 + j];
            float c = (rlab[j] == tc) ? ((s < 1.f) ? 1.f - s : 0.f)
                                      : ((s > MARGIN) ? s : 0.f);
            const int row = rowBase + rbase + j;
            float wgt = (row < col) ? 2.f : ((row == col) ? 1.f : 0.f);
            lsum += wgt * c;
          }
        }
      }
    }
  }

  // block reduce, ONE non-atomic partial store per block
#pragma unroll
  for (int off = 32; off > 0; off >>= 1) lsum += __shfl_down(lsum, off, 64);
  if (lane == 0) red[w] = lsum;
  __syncthreads();
  if (tid == 0) {
    float s = 0.f;
#pragma unroll
    for (int i = 0; i < 8; i++) s += red[i];
    partials[blockIdx.x] = s;
  }
#undef STAGE
}

// NT partials -> scalar; one 256-thread block
__global__ void reduce_kernel(const float* __restrict__ partials, float* __restrict__ out) {
  __shared__ float red[4];
  float s = 0.f;
  for (int i = threadIdx.x; i < NT; i += 256) s += partials[i];
#pragma unroll
  for (int off = 32; off > 0; off >>= 1) s += __shfl_down(s, off, 64);
  if ((threadIdx.x & 63) == 0) red[threadIdx.x >> 6] = s;
  __syncthreads();
  if (threadIdx.x == 0)
    out[0] = (red[0] + red[1] + red[2] + red[3]) * (1.0f / NROWS);
}

extern "C" void kernel_launch(void* const* d_in, const int* in_sizes, int n_in,
                              void* d_out, int out_size, void* d_ws, size_t ws_size,
                              hipStream_t stream) {
  const float* x = (const float*)d_in[0];
  const int* tg  = (const int*)d_in[1];
  float* out     = (float*)d_out;
  unsigned char* xb = (unsigned char*)d_ws;                    // fp8 X, 4 MiB
  float* partials   = (float*)((char*)d_ws + (4u << 20));      // NT floats

  convert_kernel<<<(NROWS * NDIM / 4) / 256, 256, 0, stream>>>(
      (const float4*)x, (unsigned*)xb);
  loss_kernel<<<NT, 512, 0, stream>>>(xb, tg, partials);
  reduce_kernel<<<1, 256, 0, stream>>>(partials, out);
}